// Round 3
// baseline (379.467 us; speedup 1.0000x reference)
//
#include <hip/hip_runtime.h>
#include <hip/hip_bf16.h>
#include <stdint.h>

#define B_ROWS 16384
#define D_K    2048
#define C_COLS 1000
#define C_PAD  1024
#define EPS_D2 1e-12f

typedef __attribute__((ext_vector_type(8))) short bf16x8;
typedef __attribute__((ext_vector_type(4))) float f32x4;

__device__ __forceinline__ void async16(void* lds, const void* g) {
    __builtin_amdgcn_global_load_lds(
        (const __attribute__((address_space(1))) unsigned int*)g,
        (__attribute__((address_space(3))) unsigned int*)lds,
        16, 0, 0);
}

// 4 f32 -> 4 bf16 (RNE), packed as uint2 (8 B)
__device__ __forceinline__ uint2 pack_bf16x4(float4 v) {
    union { __hip_bfloat162 h; uint32_t u; } a, b;
    a.h = __float22bfloat162_rn(make_float2(v.x, v.y));
    b.h = __float22bfloat162_rn(make_float2(v.z, v.w));
    uint2 r; r.x = a.u; r.y = b.u; return r;
}

// Wave-per-row prep for w only: fp32 -> bf16 (zero-padded rows >= C_COLS) + ||w||^2.
__global__ __launch_bounds__(256) void wprep(
    const float* __restrict__ w, __hip_bfloat16* __restrict__ wb, float* __restrict__ w2) {
    const int t = threadIdx.x;
    const int wave = t >> 6;
    const int lane = t & 63;
    const int row = blockIdx.x * 4 + wave;          // 0..1023
    const bool valid = (row < C_COLS);

    const float* src = w + (size_t)row * D_K;
    uint2* dst = (uint2*)(wb + (size_t)row * D_K);

    float4 v[8];
    if (valid) {
        const float4* s4 = (const float4*)src;
        #pragma unroll
        for (int i = 0; i < 8; i++) v[i] = s4[lane + 64 * i];
    } else {
        #pragma unroll
        for (int i = 0; i < 8; i++) v[i] = make_float4(0.f, 0.f, 0.f, 0.f);
    }
    float ss = 0.f;
    #pragma unroll
    for (int i = 0; i < 8; i++) {
        ss += v[i].x * v[i].x + v[i].y * v[i].y + v[i].z * v[i].z + v[i].w * v[i].w;
        dst[lane + 64 * i] = pack_bf16x4(v[i]);
    }
    #pragma unroll
    for (int off = 32; off > 0; off >>= 1) ss += __shfl_down(ss, off, 64);
    if (lane == 0) w2[row] = valid ? ss : 0.f;
}

// Fused: fp32 A read + in-register bf16 convert + ||x||^2, software-pipelined K-loop,
// B double-buffered via global_load_lds, MFMA 128x128 tile, LDS-staged coalesced epilogue.
__global__ __launch_bounds__(256) void dml_fused(
    const float* __restrict__ X,            // [16384, 2048] fp32
    const __hip_bfloat16* __restrict__ Wb,  // [1024, 2048] bf16 (padded)
    const float* __restrict__ w2,           // [1024]
    const float* __restrict__ scales, float* __restrict__ out)
{
    __shared__ __align__(16) char smem[8192 + 2 * 8192];     // lsA (8K) + lsB dbuf (2x8K)
    __hip_bfloat16* lsA = (__hip_bfloat16*)smem;
    __hip_bfloat16* lsB = (__hip_bfloat16*)(smem + 8192);
    float* lsC = (float*)smem;                               // epilogue alias: 32*132*4 = 16896 B
    __shared__ float sx2[128];

    const int tid  = threadIdx.x;
    const int wave = tid >> 6;
    const int lane = tid & 63;

    // XCD-aware remap (gridDim.x == 8): XCD x owns m-tiles [x*16, x*16+16).
    const int id  = blockIdx.y * 8 + blockIdx.x;
    const int xcd = id & 7;
    const int j   = id >> 3;
    const int m0  = (xcd * 16 + (j >> 3)) * 128;
    const int n0  = (j & 7) * 128;

    const int wm = wave >> 1, wn = wave & 1;

    // A staging map: thread t covers rows rA+32i (i=0..3), float4-chunk cA of the 32-float strip.
    const int rA = tid >> 3;            // 0..31
    const int cA = tid & 7;             // 0..7
    const float* gA = X + (size_t)(m0 + rA) * D_K + cA * 4;
    // swizzled LDS write: row r, 16B-slot = (cA>>1) ^ ((r>>1)&3), half = cA&1; sw(r+32)==sw(r)
    char* lAw = (char*)lsA + rA * 64 + (((cA >> 1) ^ ((rA >> 1) & 3)) * 16) + (cA & 1) * 8;

    // B staging (global_load_lds, 16B/lane, swizzled): wave covers rows wave*32+(lane>>2)+{0,16}
    const int srow = wave * 32 + (lane >> 2);
    const int slot = lane & 3;
    const int scol = (slot ^ ((srow >> 1) & 3)) * 8;
    const __hip_bfloat16* gB0 = Wb + (size_t)(n0 + srow) * D_K + scol;
    const __hip_bfloat16* gB1 = gB0 + (size_t)16 * D_K;
    const int lBoff = wave * 32 * 64 + lane * 16;            // bytes within one B buffer

    // fragment read ptrs (swizzled)
    const int fr = lane & 15, fq = lane >> 4;
    const int fsw = (fr >> 1) & 3;
    const __hip_bfloat16* fA = lsA + (wm * 64 + fr) * 32 + (fq ^ fsw) * 8;
    const int fBoff = (wn * 64 + fr) * 32 + (fq ^ fsw) * 8;  // elements within one B buffer

    f32x4 acc[4][4] = {};
    float ss[4] = {0.f, 0.f, 0.f, 0.f};

    // Prologue: prefetch A(0) into regs, B(0) into buf0.
    float4 vA[4];
    #pragma unroll
    for (int i = 0; i < 4; i++) vA[i] = *(const float4*)(gA + (size_t)i * 32 * D_K);
    async16((char*)lsB + lBoff, gB0);
    async16((char*)lsB + lBoff + 16 * 64, gB1);

    for (int k = 0; k < 64; k++) {
        const int buf = k & 1;
        __syncthreads();   // (1) drains vmcnt: vA(k) regs + B(k)->buf; lsA free (prev readers done)

        #pragma unroll
        for (int i = 0; i < 4; i++) {
            float4 v = vA[i];
            ss[i] += v.x * v.x + v.y * v.y + v.z * v.z + v.w * v.w;
            *(uint2*)(lAw + i * 2048) = pack_bf16x4(v);
        }
        __syncthreads();   // (2) drains lgkm only (A writes); no vmem pending here

        if (k < 63) {      // issue next iter's loads; they drain at barrier (1) of k+1,
                           // overlapped with this iter's MFMA section
            const float* gAn = gA + (k + 1) * 32;
            #pragma unroll
            for (int i = 0; i < 4; i++) vA[i] = *(const float4*)(gAn + (size_t)i * 32 * D_K);
            const char* src0 = (const char*)(gB0 + (k + 1) * 32);
            const char* src1 = (const char*)(gB1 + (k + 1) * 32);
            async16((char*)lsB + (buf ^ 1) * 8192 + lBoff, src0);
            async16((char*)lsB + (buf ^ 1) * 8192 + lBoff + 16 * 64, src1);
        }

        const __hip_bfloat16* fBb = lsB + buf * 4096 + fBoff;
        bf16x8 a[4], b[4];
        #pragma unroll
        for (int i = 0; i < 4; i++) a[i] = *(const bf16x8*)(fA + i * 16 * 32);
        #pragma unroll
        for (int j2 = 0; j2 < 4; j2++) b[j2] = *(const bf16x8*)(fBb + j2 * 16 * 32);
        #pragma unroll
        for (int i = 0; i < 4; i++)
            #pragma unroll
            for (int j2 = 0; j2 < 4; j2++)
                acc[i][j2] = __builtin_amdgcn_mfma_f32_16x16x32_bf16(a[i], b[j2], acc[i][j2], 0, 0, 0);
    }

    // ||x||^2 reduce: 8 threads (cA=0..7) share each row set {rA, rA+32, rA+64, rA+96}.
    #pragma unroll
    for (int i = 0; i < 4; i++) {
        float v = ss[i];
        v += __shfl_down(v, 4, 8);
        v += __shfl_down(v, 2, 8);
        v += __shfl_down(v, 1, 8);
        ss[i] = v;
    }
    if (cA == 0) {
        sx2[rA] = ss[0]; sx2[rA + 32] = ss[1]; sx2[rA + 64] = ss[2]; sx2[rA + 96] = ss[3];
    }
    __syncthreads();   // sx2 visible; all MFMA LDS reads done -> lsC alias safe

    // Epilogue: 4 phases of 32 rows; compute -s*sqrt in MFMA layout, stage via lsC (stride 132),
    // store aligned float4 rows.
    const float s = scales[0];
    const int colb = wn * 64 + fr;           // local col
    const int rowlb = wm * 64 + fq * 4;      // local row base (within 128)
    float w2v[4];
    #pragma unroll
    for (int j2 = 0; j2 < 4; j2++) w2v[j2] = w2[n0 + colb + j2 * 16];
    float x2v[4][4];
    #pragma unroll
    for (int i = 0; i < 4; i++)
        #pragma unroll
        for (int r = 0; r < 4; r++) x2v[i][r] = sx2[rowlb + i * 16 + r];

    const int rr = tid >> 3;                 // 0..31: reader row within phase
    const int gmb = m0 + (rr & 15) + (rr >> 4) * 64;
    #pragma unroll
    for (int i = 0; i < 4; i++) {
        #pragma unroll
        for (int j2 = 0; j2 < 4; j2++)
            #pragma unroll
            for (int r = 0; r < 4; r++) {
                float d2 = x2v[i][r] + w2v[j2] - 2.0f * acc[i][j2][r];
                d2 = fmaxf(d2, EPS_D2);
                lsC[(wm * 16 + fq * 4 + r) * 132 + colb + j2 * 16] = -s * __builtin_sqrtf(d2);
            }
        __syncthreads();                     // phase data visible
        {
            float* orow = out + (size_t)(gmb + i * 16) * C_COLS + n0;
            #pragma unroll
            for (int q = 0; q < 4; q++) {
                const int f = (tid & 7) + 8 * q;
                if ((n0 >> 2) + f < C_COLS / 4) {
                    float4 val = *(const float4*)(lsC + rr * 132 + f * 4);
                    *(float4*)(orow + f * 4) = val;
                }
            }
        }
        __syncthreads();                     // before next phase overwrites lsC
    }
}

extern "C" void kernel_launch(void* const* d_in, const int* in_sizes, int n_in,
                              void* d_out, int out_size, void* d_ws, size_t ws_size,
                              hipStream_t stream) {
    const float* x      = (const float*)d_in[0];
    const float* w      = (const float*)d_in[1];
    const float* scales = (const float*)d_in[2];
    float* out = (float*)d_out;

    char* ws = (char*)d_ws;
    __hip_bfloat16* wb = (__hip_bfloat16*)ws;                        // 4,194,304 B
    float* w2 = (float*)(ws + (size_t)C_PAD * D_K * 2);              // 4,096 B

    wprep<<<dim3(C_PAD / 4), dim3(256), 0, stream>>>(w, wb, w2);
    dml_fused<<<dim3(8, B_ROWS / 128), dim3(256), 0, stream>>>(x, wb, w2, scales, out);
}

// Round 4
// 307.822 us; speedup vs baseline: 1.2327x; 1.2327x over previous
//
#include <hip/hip_runtime.h>
#include <hip/hip_bf16.h>
#include <stdint.h>

#define B_ROWS 16384
#define D_K    2048
#define C_COLS 1000
#define C_PAD  1024
#define EPS_D2 1e-12f

typedef __attribute__((ext_vector_type(8))) short bf16x8;
typedef __attribute__((ext_vector_type(4))) float f32x4;

__device__ __forceinline__ void async16(void* lds, const void* g) {
    __builtin_amdgcn_global_load_lds(
        (const __attribute__((address_space(1))) unsigned int*)g,
        (__attribute__((address_space(3))) unsigned int*)lds,
        16, 0, 0);
}

// 4 f32 -> 4 bf16 (RNE) packed into uint2
__device__ __forceinline__ uint2 pack_bf16x4(float4 v) {
    union { __hip_bfloat162 h; uint32_t u; } a, b;
    a.h = __float22bfloat162_rn(make_float2(v.x, v.y));
    b.h = __float22bfloat162_rn(make_float2(v.z, v.w));
    uint2 r; r.x = a.u; r.y = b.u; return r;
}

// Wave-per-row prep: fp32 -> bf16 (RNE) + fp32 sum-of-squares.
// Rows [0,B_ROWS) = x; rows [B_ROWS, B_ROWS+C_PAD) = w (zero-padded past C_COLS).
// Per lane: 8 float4 loads (adjacent pairs) -> 4 uint4 (16 B) stores.
__global__ __launch_bounds__(256) void prep_all(
    const float* __restrict__ x, const float* __restrict__ w,
    __hip_bfloat16* __restrict__ xb, __hip_bfloat16* __restrict__ wb,
    float* __restrict__ x2, float* __restrict__ w2) {
    const int t = threadIdx.x;
    const int wave = t >> 6;
    const int lane = t & 63;
    const int row = blockIdx.x * 4 + wave;

    const float* src;
    uint4* dst;
    float* norm_out;
    bool valid;
    if (row < B_ROWS) {
        src = x + (size_t)row * D_K;
        dst = (uint4*)(xb + (size_t)row * D_K);
        norm_out = x2 + row;
        valid = true;
    } else {
        int c = row - B_ROWS;
        src = w + (size_t)c * D_K;
        dst = (uint4*)(wb + (size_t)c * D_K);
        norm_out = w2 + c;
        valid = (c < C_COLS);
    }

    float4 v[8];
    if (valid) {
        const float4* s4 = (const float4*)src;
        #pragma unroll
        for (int i = 0; i < 4; i++) {
            v[2 * i]     = s4[2 * lane + 128 * i];
            v[2 * i + 1] = s4[2 * lane + 1 + 128 * i];
        }
    } else {
        #pragma unroll
        for (int i = 0; i < 8; i++) v[i] = make_float4(0.f, 0.f, 0.f, 0.f);
    }

    float ss = 0.f;
    #pragma unroll
    for (int i = 0; i < 8; i++)
        ss += v[i].x * v[i].x + v[i].y * v[i].y + v[i].z * v[i].z + v[i].w * v[i].w;

    #pragma unroll
    for (int i = 0; i < 4; i++) {
        uint2 a = pack_bf16x4(v[2 * i]);
        uint2 b = pack_bf16x4(v[2 * i + 1]);
        uint4 p; p.x = a.x; p.y = a.y; p.z = b.x; p.w = b.y;
        dst[lane + 64 * i] = p;   // bf16 elems [8*(lane+64i), +8) == floats loaded above
    }

    #pragma unroll
    for (int off = 32; off > 0; off >>= 1) ss += __shfl_down(ss, off, 64);
    if (lane == 0 && valid) *norm_out = ss;
}

// 128x128 tile, BK=32, 256 threads = 4 waves (2x2), 4x4 MFMA 16x16x32 per wave.
// XCD-remap for A-tile L2 reuse; XOR-swizzled LDS (0 conflicts in K-loop);
// LDS-staged epilogue -> aligned float4 C stores.
__global__ __launch_bounds__(256) void dml_gemm(
    const __hip_bfloat16* __restrict__ A,   // [B_ROWS, D_K] bf16
    const __hip_bfloat16* __restrict__ Bm,  // [C_PAD, D_K] bf16 (padded)
    const float* __restrict__ x2, const float* __restrict__ w2,
    const float* __restrict__ scales, float* __restrict__ out)
{
    __shared__ __align__(16) char smem[32 * 132 * 4];        // 16896 B: K-loop uses first 16384
    __hip_bfloat16* lsA = (__hip_bfloat16*)smem;             // 8192 B
    __hip_bfloat16* lsB = (__hip_bfloat16*)(smem + 8192);    // 8192 B
    float* lsC = (float*)smem;                                // epilogue alias, stride 132

    const int tid  = threadIdx.x;
    const int wave = tid >> 6;
    const int lane = tid & 63;

    // XCD-aware remap (gridDim.x == 8): XCD x owns m-tiles [x*16, x*16+16).
    const int id  = blockIdx.y * 8 + blockIdx.x;
    const int xcd = id & 7;
    const int j   = id >> 3;
    const int m0  = (xcd * 16 + (j >> 3)) * 128;
    const int n0  = (j & 7) * 128;

    const int wm = wave >> 1;
    const int wn = wave & 1;

    // Staging: lane covers (srow, slot); global chunk = slot ^ ((srow>>1)&3) (swizzle).
    const int srow = wave * 32 + (lane >> 2);
    const int slot = lane & 3;
    const int scol = (slot ^ ((srow >> 1) & 3)) * 8;
    const __hip_bfloat16* gA0 = A  + (size_t)(m0 + srow) * D_K + scol;
    const __hip_bfloat16* gA1 = gA0 + (size_t)16 * D_K;
    const __hip_bfloat16* gB0 = Bm + (size_t)(n0 + srow) * D_K + scol;
    const __hip_bfloat16* gB1 = gB0 + (size_t)16 * D_K;
    char* lA0 = (char*)lsA + wave * 32 * 64 + lane * 16;
    char* lA1 = lA0 + 16 * 64;
    char* lB0 = (char*)lsB + wave * 32 * 64 + lane * 16;
    char* lB1 = lB0 + 16 * 64;

    // Fragment read ptrs (swizzled): row R in {.., fr mod 16 ..}: sw depends only on (fr>>1)&3
    const int fr  = lane & 15;
    const int fq  = lane >> 4;
    const int fsw = (fr >> 1) & 3;
    const __hip_bfloat16* fA = lsA + (wm * 64 + fr) * 32 + (fq ^ fsw) * 8;
    const __hip_bfloat16* fB = lsB + (wn * 64 + fr) * 32 + (fq ^ fsw) * 8;

    f32x4 acc[4][4] = {};

    for (int k0 = 0; k0 < D_K; k0 += 32) {
        __syncthreads();               // LDS safe to overwrite
        async16(lA0, gA0); async16(lA1, gA1);
        async16(lB0, gB0); async16(lB1, gB1);
        gA0 += 32; gA1 += 32; gB0 += 32; gB1 += 32;
        __syncthreads();               // drains vmcnt -> staged data visible

        bf16x8 a[4], b[4];
        #pragma unroll
        for (int i = 0; i < 4; i++) a[i] = *(const bf16x8*)(fA + i * 16 * 32);
        #pragma unroll
        for (int j2 = 0; j2 < 4; j2++) b[j2] = *(const bf16x8*)(fB + j2 * 16 * 32);
        #pragma unroll
        for (int i = 0; i < 4; i++)
            #pragma unroll
            for (int j2 = 0; j2 < 4; j2++)
                acc[i][j2] = __builtin_amdgcn_mfma_f32_16x16x32_bf16(a[i], b[j2], acc[i][j2], 0, 0, 0);
    }

    // Epilogue: -s*sqrt(max(x2+w2-2*acc, eps)), staged through lsC for coalesced stores.
    const float s = scales[0];
    const int colb  = wn * 64 + fr;          // local col (C/D: col = lane&15)
    const int rowlb = wm * 64 + fq * 4;      // local row base (C/D: row = fq*4 + reg)

    float w2v[4];
    #pragma unroll
    for (int j2 = 0; j2 < 4; j2++) w2v[j2] = w2[n0 + colb + j2 * 16];
    float x2v[4][4];
    #pragma unroll
    for (int i = 0; i < 4; i++)
        #pragma unroll
        for (int r = 0; r < 4; r++) x2v[i][r] = x2[m0 + rowlb + i * 16 + r];

    __syncthreads();   // all K-loop LDS reads done -> lsC alias safe

    // 4 phases of 32 rows. Writer: row-in-phase = wm*16 + fq*4 + r (2-way bank = free).
    // Reader: rr = tid>>3 covers the 32 rows; 4 aligned float4 per thread.
    const int rr  = tid >> 3;
    const int gmb = m0 + (rr & 15) + (rr >> 4) * 64;
    #pragma unroll
    for (int i = 0; i < 4; i++) {
        #pragma unroll
        for (int j2 = 0; j2 < 4; j2++)
            #pragma unroll
            for (int r = 0; r < 4; r++) {
                float d2 = x2v[i][r] + w2v[j2] - 2.0f * acc[i][j2][r];
                d2 = fmaxf(d2, EPS_D2);
                lsC[(wm * 16 + fq * 4 + r) * 132 + colb + j2 * 16] = -s * __builtin_sqrtf(d2);
            }
        __syncthreads();
        {
            float* orow = out + (size_t)(gmb + i * 16) * C_COLS + n0;
            #pragma unroll
            for (int q = 0; q < 4; q++) {
                const int f = (tid & 7) + 8 * q;
                if ((n0 >> 2) + f < C_COLS / 4) {
                    float4 val = *(const float4*)(lsC + rr * 132 + f * 4);
                    *(float4*)(orow + f * 4) = val;
                }
            }
        }
        __syncthreads();
    }
}

extern "C" void kernel_launch(void* const* d_in, const int* in_sizes, int n_in,
                              void* d_out, int out_size, void* d_ws, size_t ws_size,
                              hipStream_t stream) {
    const float* x      = (const float*)d_in[0];
    const float* w      = (const float*)d_in[1];
    const float* scales = (const float*)d_in[2];
    float* out = (float*)d_out;

    char* ws = (char*)d_ws;
    __hip_bfloat16* xb = (__hip_bfloat16*)ws;                                  // 67,108,864 B
    __hip_bfloat16* wb = (__hip_bfloat16*)(ws + (size_t)B_ROWS * D_K * 2);     //  4,194,304 B
    float* x2 = (float*)(ws + (size_t)B_ROWS * D_K * 2 + (size_t)C_PAD * D_K * 2);
    float* w2 = x2 + B_ROWS;

    prep_all<<<dim3((B_ROWS + C_PAD) / 4), dim3(256), 0, stream>>>(x, w, xb, wb, x2, w2);
    dml_gemm<<<dim3(8, B_ROWS / 128), dim3(256), 0, stream>>>(xb, wb, x2, w2, scales, out);
}